// Round 11
// baseline (129.247 us; speedup 1.0000x reference)
//
#include <hip/hip_runtime.h>

// VQ-VAE quantizer forward. fp8-e4m3 MFMA scores (z*2^4, W*2^14, argmin
// scale-invariant). M=32 rows/block, 1024 blocks -> 4 blocks/CU. W staged
// into LDS via global_load_lds double-buffer with counted vmcnt(2) (never
// drained in-loop); A and B both read from LDS (2-way-free banks); argmin
// state in regs (~95 total) so __launch_bounds__(256,4) holds 4 waves/SIMD.
// mse from the score accumulator; quantized gathered from a bf16 W copy.
// z: [32, 256, 32, 32] fp32; weight: [256, 1024] fp32.
// out: quantized [8388608] ++ loss [32768] ++ commitment [32768] ++ embedding [32768]

typedef unsigned short ushort_t;
typedef short          s16x8  __attribute__((ext_vector_type(8)));
typedef float          f32x16 __attribute__((ext_vector_type(16)));

__device__ __forceinline__ ushort_t f2bf(float x) {
    unsigned int u = __float_as_uint(x);
    u += 0x7fffu + ((u >> 16) & 1u);          // RNE
    return (ushort_t)(u >> 16);
}
__device__ __forceinline__ float bf2f(ushort_t h) {
    return __uint_as_float(((unsigned int)h) << 16);
}

__device__ __forceinline__ void dma16(const void* g, const void* l) {
    __builtin_amdgcn_global_load_lds(
        (const __attribute__((address_space(1))) unsigned int*)(unsigned long long)(uintptr_t)g,
        (__attribute__((address_space(3))) unsigned int*)(unsigned int)(uintptr_t)l,
        16, 0, 0);
}

// ---- prep: transpose W -> bf16 k-major copy, stage-linear scaled fp8 slab, wsq*2^18 ----
// fp8 slab byte: ((k>>8)*8 + (d>>5))*8192 + (((d>>4)&1)*2 + ((d>>3)&1))*2048 + (k&255)*8 + (d&7)
// (stage s of chunk c = 8192 bytes, linear in DMA lane order; B-frag reads 2-way-free)
__global__ __launch_bounds__(256)
void vq_wprep(const float* __restrict__ w,
              ushort_t* __restrict__ wbf, unsigned char* __restrict__ wf8,
              float* __restrict__ wsq18) {
    __shared__ float tile[64][65];
    __shared__ float psum[64][4];
    const int t  = threadIdx.x;
    const int kt = blockIdx.x;          // 16 blocks, 64 codes each
    const int kk = t >> 2;              // k-local 0..63
    const int dq = t & 3;               // d-octet selector within 32-d group
    const int k  = kt * 64 + kk;
    float acc = 0.f;
    for (int dt6 = 0; dt6 < 4; ++dt6) {
        __syncthreads();
        #pragma unroll
        for (int i = 0; i < 16; ++i) {
            const int lin = t + 256 * i;
            const int dd = lin >> 6, k2 = lin & 63;
            tile[dd][k2] = w[(size_t)(dt6 * 64 + dd) * 1024 + kt * 64 + k2];
        }
        __syncthreads();
        #pragma unroll
        for (int half = 0; half < 2; ++half) {
            s16x8 hv; float vs[8];
            #pragma unroll
            for (int e = 0; e < 8; ++e) {
                const int dd = half * 32 + dq * 8 + e;
                const float v = tile[dd][kk];
                hv[e] = (short)f2bf(v);
                vs[e] = v * 16384.f;              // 2^14 scale for fp8
                acc = fmaf(v, v, acc);
            }
            const int dbase = dt6 * 64 + half * 32 + dq * 8;
            *reinterpret_cast<s16x8*>(&wbf[(size_t)k * 256 + dbase]) = hv;
            unsigned plo = 0, phi = 0;
            plo = __builtin_amdgcn_cvt_pk_fp8_f32(vs[0], vs[1], plo, false);
            plo = __builtin_amdgcn_cvt_pk_fp8_f32(vs[2], vs[3], plo, true);
            phi = __builtin_amdgcn_cvt_pk_fp8_f32(vs[4], vs[5], phi, false);
            phi = __builtin_amdgcn_cvt_pk_fp8_f32(vs[6], vs[7], phi, true);
            const size_t byte = (size_t)((k >> 8) * 8 + (dbase >> 5)) * 8192
                              + (size_t)dq * 2048 + (size_t)(k & 255) * 8;
            *reinterpret_cast<unsigned*>(&wf8[byte])     = plo;
            *reinterpret_cast<unsigned*>(&wf8[byte + 4]) = phi;
        }
    }
    psum[kk][dq] = acc;
    __syncthreads();
    if (t < 64)
        wsq18[kt * 64 + t] = (psum[t][0] + psum[t][1] + psum[t][2] + psum[t][3])
                             * 262144.f;   // 2^18
}

// ---- main: M=32 rows/block, 1024 blocks, 4 blocks/CU ----
__global__ __launch_bounds__(256, 4)
void vq_mfma(const float* __restrict__ z,
             const unsigned char* __restrict__ wf8, const ushort_t* __restrict__ wbf,
             const float* __restrict__ wsq18, float* __restrict__ out) {
    __shared__ __align__(16) unsigned char wbuf[2][8192];   // W stage double-buffer
    __shared__ unsigned char z_f8[32][264];                 // [n][d]; 2-way banks
    __shared__ float psum[32][32];                          // z^2 partials [dr][n]
    __shared__ float wred_v[4][32];
    __shared__ int   wred_i[4][32];
    __shared__ int   kbest[32];

    const int tid  = threadIdx.x;
    const int bid  = blockIdx.x;
    const int b    = bid >> 5;          // 32 blocks per 1024-elem HW plane
    const int s0   = (bid & 31) * 32;
    const int lane = tid & 63;
    const int wk   = tid >> 6;          // wave id -> k-quarter of each 256-chunk
    const int l31  = lane & 31;
    const int lhi  = lane >> 5;

    // ---- stage z -> fp8 (x2^4) + z^2 partials (z read ONCE) ----
    {
        const int u  = tid & 7;
        const int sc = u * 4;
        const int dr = tid >> 3;        // 0..31
        float p[4] = {0.f, 0.f, 0.f, 0.f};
        #pragma unroll
        for (int it = 0; it < 8; ++it) {
            const int d = it * 32 + dr;
            const float4 v = *reinterpret_cast<const float4*>(
                &z[(((size_t)(b * 256 + d)) << 10) + s0 + sc]);
            const float vv[4] = {v.x, v.y, v.z, v.w};
            #pragma unroll
            for (int jj = 0; jj < 4; ++jj) {
                const int j = (jj + u) & 3;           // stagger write banks
                const int r8 = __builtin_amdgcn_cvt_pk_fp8_f32(vv[j] * 16.f, 0.f, 0, false);
                z_f8[sc + j][d] = (unsigned char)(r8 & 0xff);
                p[j] = fmaf(vv[j], vv[j], p[j]);
            }
        }
        #pragma unroll
        for (int j = 0; j < 4; ++j) psum[dr][sc + j] = p[j];
    }

    // preload wsq (scaled) so the main loop's vmcnt stream is DMA-only
    float wq8[4][2];
    #pragma unroll
    for (int c = 0; c < 4; ++c)
        #pragma unroll
        for (int nt = 0; nt < 2; ++nt)
            wq8[c][nt] = wsq18[c * 256 + wk * 64 + nt * 32 + l31];

    __syncthreads();   // z_f8/psum visible; drains staging vmem

#define ISSUE_STAGE(SN, BUF) do {                                              \
        const unsigned char* _src = wf8 + (size_t)(SN) * 8192                  \
                                  + wk * 2048 + (lane & 63) * 16;              \
        unsigned char* _dst = &wbuf[(BUF)][wk * 2048];                         \
        dma16(_src, _dst);                                                     \
        dma16(_src + 1024, _dst + 1024);                                       \
    } while (0)

    // DMA prologue: stages 0,1
    ISSUE_STAGE(0, 0);
    ISSUE_STAGE(1, 1);

    float bestv[16];
    int   besti[16];
    #pragma unroll
    for (int r = 0; r < 16; ++r) { bestv[r] = 1e30f; besti[r] = 0; }

    f32x16 acc[2];
    #pragma unroll
    for (int c = 0; c < 4; ++c) {           // k-chunks of 256 (fully unrolled)
        #pragma unroll
        for (int nt = 0; nt < 2; ++nt)
            #pragma unroll
            for (int e = 0; e < 16; ++e) acc[nt][e] = 0.f;

        #pragma unroll
        for (int s8 = 0; s8 < 8; ++s8) {    // 32-d stages; buf = s8&1 (compile-time)
            asm volatile("s_waitcnt vmcnt(2)" ::: "memory");  // stage s landed; s+1 in flight
            __builtin_amdgcn_s_barrier();
            __builtin_amdgcn_sched_barrier(0);
            #pragma unroll
            for (int jl = 0; jl < 2; ++jl) {
                const int j = s8 * 2 + jl;
                const long av = *reinterpret_cast<const long*>(
                    &z_f8[l31][j * 16 + lhi * 8]);
                const unsigned char* bp =
                    &wbuf[s8 & 1][(jl * 2 + lhi) * 2048 + (wk * 64 + l31) * 8];
                const long b0 = *reinterpret_cast<const long*>(bp);
                const long b1 = *reinterpret_cast<const long*>(bp + 256);  // nt=1: +32k*8B
                acc[0] = __builtin_amdgcn_mfma_f32_32x32x16_fp8_fp8(av, b0, acc[0], 0, 0, 0);
                acc[1] = __builtin_amdgcn_mfma_f32_32x32x16_fp8_fp8(av, b1, acc[1], 0, 0, 0);
            }
            __builtin_amdgcn_sched_barrier(0);
            __builtin_amdgcn_s_barrier();   // all reads of wbuf[s8&1] done
            // issue stage s+2 into the buffer just consumed (wrap at tail: harmless,
            // keeps the vmcnt count exact)
            ISSUE_STAGE((c * 8 + s8 + 2) & 31, s8 & 1);
        }

        // fold chunk into running argmin (dist_scaled = wsq*2^18 - 2*score*2^18)
        #pragma unroll
        for (int nt = 0; nt < 2; ++nt) {
            const int kcol = c * 256 + wk * 64 + nt * 32 + l31;
            const float wq = wq8[c][nt];
            #pragma unroll
            for (int r = 0; r < 16; ++r) {
                const float dist = fmaf(-2.f, acc[nt][r], wq);
                if (dist < bestv[r]) { bestv[r] = dist; besti[r] = kcol; }
            }
        }
    }
#undef ISSUE_STAGE

    // ---- in-wave argmin across the 32 k-lanes ----
    #pragma unroll
    for (int off = 1; off < 32; off <<= 1) {
        #pragma unroll
        for (int r = 0; r < 16; ++r) {
            const float ov = __shfl_xor(bestv[r], off);
            const int   oi = __shfl_xor(besti[r], off);
            if (ov < bestv[r] || (ov == bestv[r] && oi < besti[r])) {
                bestv[r] = ov; besti[r] = oi;
            }
        }
    }
    if (l31 == 0) {
        #pragma unroll
        for (int r = 0; r < 16; ++r) {
            const int n = (r & 3) + 8 * (r >> 2) + 4 * lhi;   // 0..31
            wred_v[wk][n] = bestv[r];
            wred_i[wk][n] = besti[r];
        }
    }
    __syncthreads();   // also drains the harmless tail DMAs

    // ---- final per-row reduce + loss outputs (mse from score accumulator) ----
    if (tid < 32) {
        float v  = wred_v[0][tid];
        int   i0 = wred_i[0][tid];
        #pragma unroll
        for (int wv = 1; wv < 4; ++wv) {
            const float ov = wred_v[wv][tid];
            const int   oi = wred_i[wv][tid];
            if (ov < v || (ov == v && oi < i0)) { v = ov; i0 = oi; }
        }
        kbest[tid] = i0;
        float zs = 0.f;
        #pragma unroll
        for (int r = 0; r < 32; ++r) zs += psum[r][tid];
        const float mse = (zs + v * 0x1p-18f) * (1.f / 256.f);  // zsq - 2*score + wsq
        const size_t n = (size_t)bid * 32 + tid;
        out[8388608 + n] = 1.25f * mse;   // loss = (beta=0.25)*mse + mse
        out[8421376 + n] = mse;           // commitment
        out[8454144 + n] = mse;           // embedding
    }
    __syncthreads();

    // ---- quantized epilogue: gather bf16 code row, coalesced writes ----
    const int es = tid & 31;            // row (s-offset)
    const int dg = tid >> 5;            // 0..7 -> 32 d each
    const int kb = kbest[es];
    const size_t base = (size_t)kb * 256 + dg * 32;
    #pragma unroll
    for (int part = 0; part < 4; ++part) {
        const s16x8 qh = *reinterpret_cast<const s16x8*>(&wbf[base + part * 8]);
        #pragma unroll
        for (int e = 0; e < 8; ++e) {
            const int d = dg * 32 + part * 8 + e;
            out[(((size_t)(b * 256 + d)) << 10) + s0 + es] = bf2f((ushort_t)qh[e]);
        }
    }
}

extern "C" void kernel_launch(void* const* d_in, const int* in_sizes, int n_in,
                              void* d_out, int out_size, void* d_ws, size_t ws_size,
                              hipStream_t stream) {
    const float* z = (const float*)d_in[0];
    const float* w = (const float*)d_in[1];
    float* out = (float*)d_out;

    float*         wsq18 = (float*)d_ws;                               // 4 KB
    unsigned char* wf8   = (unsigned char*)((char*)d_ws + 4096);       // 256 KB stage-linear fp8
    ushort_t*      wbf   = (ushort_t*)((char*)d_ws + 4096 + 262144);   // 512 KB bf16 copy

    vq_wprep<<<16,   256, 0, stream>>>(w, wbf, wf8, wsq18);
    vq_mfma <<<1024, 256, 0, stream>>>(z, wf8, wbf, wsq18, out);
}

// Round 13
// 48.907 us; speedup vs baseline: 2.6427x; 2.6427x over previous
//
#include <hip/hip_runtime.h>

// VQ-VAE quantizer forward. Scores via fp8-e4m3 MFMA (scaled: z*2^4, W*2^14,
// argmin scale-invariant), depth-8 global->reg B ring, A fp8 frags
// register-resident. Streaming z loads / out stores are NON-TEMPORAL so the
// W slabs stay L2-resident (B loads = L2 hits inside the ring's coverage).
// mse from the score accumulator; quantized gathered from a bf16 W copy.
// z: [32, 256, 32, 32] fp32; weight: [256, 1024] fp32.
// out: quantized [8388608] ++ loss [32768] ++ commitment [32768] ++ embedding [32768]

typedef unsigned short ushort_t;
typedef short          s16x8  __attribute__((ext_vector_type(8)));
typedef float          f32x4  __attribute__((ext_vector_type(4)));
typedef float          f32x16 __attribute__((ext_vector_type(16)));

__device__ __forceinline__ ushort_t f2bf(float x) {
    unsigned int u = __float_as_uint(x);
    u += 0x7fffu + ((u >> 16) & 1u);          // RNE
    return (ushort_t)(u >> 16);
}
__device__ __forceinline__ float bf2f(ushort_t h) {
    return __uint_as_float(((unsigned int)h) << 16);
}

// ---- prep: transpose W; emit bf16 k-major copy, scaled fp8 slab, wsq*2^18 ----
// fp8 slab (byte idx): (d>>4)*16384 + k*16 + (d&15)    [16 d-groups of 1024k x 16d]
// bf16 copy (ushort idx): k*256 + d
__global__ __launch_bounds__(256)
void vq_wprep(const float* __restrict__ w,
              ushort_t* __restrict__ wbf, unsigned char* __restrict__ wf8,
              float* __restrict__ wsq18) {
    __shared__ float tile[64][65];
    __shared__ float psum[64][4];
    const int t  = threadIdx.x;
    const int kt = blockIdx.x;          // 16 blocks, 64 codes each
    const int kk = t >> 2;              // k-local 0..63
    const int dq = t & 3;               // d-eighth-of-32 selector
    const int k  = kt * 64 + kk;
    float acc = 0.f;
    for (int dt6 = 0; dt6 < 4; ++dt6) {
        __syncthreads();
        #pragma unroll
        for (int i = 0; i < 16; ++i) {
            const int lin = t + 256 * i;
            const int dd = lin >> 6, k2 = lin & 63;
            tile[dd][k2] = w[(size_t)(dt6 * 64 + dd) * 1024 + kt * 64 + k2];
        }
        __syncthreads();
        #pragma unroll
        for (int half = 0; half < 2; ++half) {
            s16x8 hv;
            float vs[8];
            #pragma unroll
            for (int e = 0; e < 8; ++e) {
                const int dd = half * 32 + dq * 8 + e;
                const float v = tile[dd][kk];
                hv[e] = (short)f2bf(v);
                vs[e] = v * 16384.f;              // 2^14 scale for fp8
                acc = fmaf(v, v, acc);
            }
            // bf16 k-major copy
            const int dbase = dt6 * 64 + half * 32 + dq * 8;
            *reinterpret_cast<s16x8*>(&wbf[(size_t)k * 256 + dbase]) = hv;
            // fp8 packed 8 bytes
            unsigned plo = 0, phi = 0;
            plo = __builtin_amdgcn_cvt_pk_fp8_f32(vs[0], vs[1], plo, false);
            plo = __builtin_amdgcn_cvt_pk_fp8_f32(vs[2], vs[3], plo, true);
            phi = __builtin_amdgcn_cvt_pk_fp8_f32(vs[4], vs[5], phi, false);
            phi = __builtin_amdgcn_cvt_pk_fp8_f32(vs[6], vs[7], phi, true);
            const int dgrp = dbase >> 4;          // = dt6*4 + half*2 + (dq>>1)
            const size_t off = (size_t)dgrp * 16384 + (size_t)k * 16 + (dq & 1) * 8;
            *reinterpret_cast<unsigned*>(&wf8[off])     = plo;
            *reinterpret_cast<unsigned*>(&wf8[off + 4]) = phi;
        }
    }
    psum[kk][dq] = acc;
    __syncthreads();
    if (t < 64)
        wsq18[kt * 64 + t] = (psum[t][0] + psum[t][1] + psum[t][2] + psum[t][3])
                             * 262144.f;   // 2^18
}

// ---- main: M=64 rows/block, 512 blocks, 2 blocks/CU ----
__global__ __launch_bounds__(256, 2)
void vq_mfma(const float* __restrict__ z,
             const unsigned char* __restrict__ wf8, const ushort_t* __restrict__ wbf,
             const float* __restrict__ wsq18, float* __restrict__ out) {
    __shared__ unsigned char z_f8[64][264];   // [n][d] bytes; row stride 264 -> 2-way banks
    __shared__ float psum[16][64];            // z^2 partials [dr][s]
    __shared__ float wred_v[4][64];
    __shared__ int   wred_i[4][64];
    __shared__ int   kbest[64];

    const int tid  = threadIdx.x;
    const int bid  = blockIdx.x;
    const int b    = bid >> 4;
    const int s0   = (bid & 15) * 64;
    const int lane = tid & 63;
    const int wk   = tid >> 6;      // wave id -> k-quarter of each 256-chunk
    const int l31  = lane & 31;
    const int lhi  = lane >> 5;

    // ---- stage z -> fp8 (x2^4) + z^2 partials (z read ONCE, non-temporal) ----
    {
        const int u  = tid & 15;
        const int sc = u * 4;
        const int dr = tid >> 4;      // 0..15
        float p[4] = {0.f, 0.f, 0.f, 0.f};
        for (int it = 0; it < 16; ++it) {
            const int d = it * 16 + dr;
            const f32x4 v = __builtin_nontemporal_load(
                reinterpret_cast<const f32x4*>(
                    &z[(((size_t)(b * 256 + d)) << 10) + s0 + sc]));
            #pragma unroll
            for (int jj = 0; jj < 4; ++jj) {
                const int j = (jj + u) & 3;           // stagger write banks
                const float zv = v[j];
                const int r8 = __builtin_amdgcn_cvt_pk_fp8_f32(zv * 16.f, 0.f, 0, false);
                z_f8[sc + j][d] = (unsigned char)(r8 & 0xff);
                p[j] = fmaf(zv, zv, p[j]);
            }
        }
        #pragma unroll
        for (int j = 0; j < 4; ++j) psum[dr][sc + j] = p[j];
    }
    __syncthreads();

    // ---- A fragments -> registers (row = m*32+l31, d = j*16 + lhi*8 + e) ----
    long a[2][16];
    #pragma unroll
    for (int m = 0; m < 2; ++m)
        #pragma unroll
        for (int j = 0; j < 16; ++j)
            a[m][j] = *reinterpret_cast<const long*>(&z_f8[m * 32 + l31][j * 16 + lhi * 8]);

    const size_t lane_k16 = (size_t)(wk * 64 + l31) * 16 + lhi * 8;

    float bestv[2][16];
    int   besti[2][16];
    #pragma unroll
    for (int m = 0; m < 2; ++m)
        #pragma unroll
        for (int r = 0; r < 16; ++r) { bestv[m][r] = 1e30f; besti[m][r] = 0; }

    long   bb[8][2];
    f32x16 acc[2][2];
    for (int c = 0; c < 4; ++c) {           // k-chunks of 256 (rolled)
        #pragma unroll
        for (int m = 0; m < 2; ++m)
            #pragma unroll
            for (int nt = 0; nt < 2; ++nt)
                #pragma unroll
                for (int e = 0; e < 16; ++e) acc[m][nt][e] = 0.f;

        // depth-8 preamble: steps j=0..7 of this chunk
        #pragma unroll
        for (int p = 0; p < 8; ++p) {
            const unsigned char* src = wf8 + (size_t)p * 16384 + (size_t)c * 4096 + lane_k16;
            bb[p][0] = *reinterpret_cast<const long*>(src);
            bb[p][1] = *reinterpret_cast<const long*>(src + 512);
        }

        #pragma unroll
        for (int j = 0; j < 16; ++j) {
            const int slot = j & 7;                     // compile-time
            acc[0][0] = __builtin_amdgcn_mfma_f32_32x32x16_fp8_fp8(
                a[0][j], bb[slot][0], acc[0][0], 0, 0, 0);
            acc[1][0] = __builtin_amdgcn_mfma_f32_32x32x16_fp8_fp8(
                a[1][j], bb[slot][0], acc[1][0], 0, 0, 0);
            acc[0][1] = __builtin_amdgcn_mfma_f32_32x32x16_fp8_fp8(
                a[0][j], bb[slot][1], acc[0][1], 0, 0, 0);
            acc[1][1] = __builtin_amdgcn_mfma_f32_32x32x16_fp8_fp8(
                a[1][j], bb[slot][1], acc[1][1], 0, 0, 0);
            // prefetch step j+8 into the slot just consumed (WAR keeps order)
            if (j + 8 < 16) {
                const unsigned char* src = wf8 + (size_t)(j + 8) * 16384
                                         + (size_t)c * 4096 + lane_k16;
                bb[slot][0] = *reinterpret_cast<const long*>(src);
                bb[slot][1] = *reinterpret_cast<const long*>(src + 512);
            }
        }

        // fold chunk into running argmin (dist_scaled = wsq*2^18 - 2*score_scaled)
        #pragma unroll
        for (int nt = 0; nt < 2; ++nt) {
            const int kcol = c * 256 + wk * 64 + nt * 32 + l31;
            const float wq = wsq18[kcol];
            #pragma unroll
            for (int m = 0; m < 2; ++m)
                #pragma unroll
                for (int r = 0; r < 16; ++r) {
                    const float dist = fmaf(-2.f, acc[m][nt][r], wq);
                    if (dist < bestv[m][r]) { bestv[m][r] = dist; besti[m][r] = kcol; }
                }
        }
    }

    // ---- in-wave argmin across the 32 k-lanes ----
    #pragma unroll
    for (int off = 1; off < 32; off <<= 1) {
        #pragma unroll
        for (int m = 0; m < 2; ++m)
            #pragma unroll
            for (int r = 0; r < 16; ++r) {
                const float ov = __shfl_xor(bestv[m][r], off);
                const int   oi = __shfl_xor(besti[m][r], off);
                if (ov < bestv[m][r] || (ov == bestv[m][r] && oi < besti[m][r])) {
                    bestv[m][r] = ov; besti[m][r] = oi;
                }
            }
    }
    if (l31 == 0) {
        #pragma unroll
        for (int m = 0; m < 2; ++m)
            #pragma unroll
            for (int r = 0; r < 16; ++r) {
                const int n = m * 32 + (r & 3) + 8 * (r >> 2) + 4 * lhi;
                wred_v[wk][n] = bestv[m][r];
                wred_i[wk][n] = besti[m][r];
            }
    }
    __syncthreads();

    // ---- final per-row reduce + loss outputs (mse from score accumulator) ----
    if (tid < 64) {
        float v  = wred_v[0][tid];
        int   i0 = wred_i[0][tid];
        #pragma unroll
        for (int wv = 1; wv < 4; ++wv) {
            const float ov = wred_v[wv][tid];
            const int   oi = wred_i[wv][tid];
            if (ov < v || (ov == v && oi < i0)) { v = ov; i0 = oi; }
        }
        kbest[tid] = i0;
        float zs = 0.f;
        #pragma unroll
        for (int r = 0; r < 16; ++r) zs += psum[r][tid];
        const float mse = (zs + v * 0x1p-18f) * (1.f / 256.f);  // zsq - 2*score + wsq
        const size_t n = (size_t)bid * 64 + tid;
        __builtin_nontemporal_store(1.25f * mse, &out[8388608 + n]);  // loss
        __builtin_nontemporal_store(mse,         &out[8421376 + n]);  // commitment
        __builtin_nontemporal_store(mse,         &out[8454144 + n]);  // embedding
    }
    __syncthreads();

    // ---- quantized epilogue: gather bf16 code row, non-temporal coalesced writes ----
    const int es = tid & 63;
    const int dg = tid >> 6;            // 0..3 -> d-range dg*64..+63
    const int kb = kbest[es];
    #pragma unroll
    for (int si = 0; si < 2; ++si) {
        const size_t base = (size_t)kb * 256 + (dg * 2 + si) * 32;
        #pragma unroll
        for (int part = 0; part < 4; ++part) {
            const s16x8 qh = *reinterpret_cast<const s16x8*>(&wbf[base + part * 8]);
            #pragma unroll
            for (int e = 0; e < 8; ++e) {
                const int d = (dg * 2 + si) * 32 + part * 8 + e;
                __builtin_nontemporal_store(
                    bf2f((ushort_t)qh[e]),
                    &out[(((size_t)(b * 256 + d)) << 10) + s0 + es]);
            }
        }
    }
}

extern "C" void kernel_launch(void* const* d_in, const int* in_sizes, int n_in,
                              void* d_out, int out_size, void* d_ws, size_t ws_size,
                              hipStream_t stream) {
    const float* z = (const float*)d_in[0];
    const float* w = (const float*)d_in[1];
    float* out = (float*)d_out;

    float*         wsq18 = (float*)d_ws;                               // 4 KB
    unsigned char* wf8   = (unsigned char*)((char*)d_ws + 4096);       // 256 KB scaled fp8
    ushort_t*      wbf   = (ushort_t*)((char*)d_ws + 4096 + 262144);   // 512 KB bf16 copy

    vq_wprep<<<16,  256, 0, stream>>>(w, wbf, wf8, wsq18);
    vq_mfma <<<512, 256, 0, stream>>>(z, wf8, wbf, wsq18, out);
}